// Round 1
// baseline (648.274 us; speedup 1.0000x reference)
//
#include <hip/hip_runtime.h>
#include <math.h>

#define B_TOTAL 65536
#define IN_DIM 512
#define HID_DIM 512
#define FAN1 1024
#define NQ 8
#define NGATES 4

// ---------------------------------------------------------------------------
// Kernel 1: Z[b][g*8+q] = tanh( sum_i combined[b][i] * W1[g][q][i] + b1[g][q] )
//   combined = concat(x, h) along feature dim (1024).
//   Block: 256 threads = 4 waves, 64 batch rows per block.
//   Wave w == gate g: computes q=0..7 for all 64 rows (1 row per lane,
//   8 fp32 accumulators per lane). W1 read via uniform (scalar) loads.
//   Combined tile staged in LDS with XOR swizzle -> conflict-free b128 reads.
// ---------------------------------------------------------------------------
__global__ __launch_bounds__(256, 4)
void k1_gemv(const float* __restrict__ x, const float* __restrict__ h,
             const float* __restrict__ W1, const float* __restrict__ b1,
             float* __restrict__ Z) {
    __shared__ __align__(16) float tile[64][64];  // 16 KB

    const int tid     = threadIdx.x;
    const int lane    = tid & 63;
    // wave id (== gate g). readfirstlane makes it uniform-by-construction so
    // all W1/b1 addressing becomes scalar (s_load) instead of vector loads.
    const int g       = __builtin_amdgcn_readfirstlane(tid >> 6);
    const int rowbase = blockIdx.x * 64;

    float acc[8];
#pragma unroll
    for (int j = 0; j < 8; ++j) acc[j] = 0.0f;

    for (int kc = 0; kc < FAN1; kc += 64) {
        const float* src = (kc < IN_DIM) ? (x + kc) : (h + (kc - IN_DIM));

        __syncthreads();  // protect tile against readers of previous chunk
        // Stage 64 rows x 64 cols, float4 per thread x4, coalesced 256B/row.
#pragma unroll
        for (int i = 0; i < 4; ++i) {
            int idx = tid + 256 * i;
            int r   = idx >> 4;          // 0..63
            int kg  = idx & 15;          // float4 group 0..15
            float4 v = *(const float4*)(src + (size_t)(rowbase + r) * 512 + kg * 4);
            // XOR swizzle on the float4-group index -> conflict-free reads
            *(float4*)&tile[r][(kg ^ (r & 7)) << 2] = v;
        }
        __syncthreads();

#pragma unroll 2
        for (int kg = 0; kg < 16; ++kg) {
            float4 cv = *(const float4*)&tile[lane][(kg ^ (lane & 7)) << 2];
#pragma unroll
            for (int j = 0; j < 8; ++j) {
                // uniform address -> s_load_dwordx4
                float4 wv = *(const float4*)(W1 + (size_t)(g * 8 + j) * FAN1 + kc + kg * 4);
                acc[j] = fmaf(cv.x, wv.x, acc[j]);
                acc[j] = fmaf(cv.y, wv.y, acc[j]);
                acc[j] = fmaf(cv.z, wv.z, acc[j]);
                acc[j] = fmaf(cv.w, wv.w, acc[j]);
            }
        }
    }

    // Epilogue: bias + tanh, write Z row-slice (8 consecutive floats).
    float o[8];
#pragma unroll
    for (int j = 0; j < 8; ++j) {
        o[j] = tanhf(acc[j] + b1[g * 8 + j]);
    }
    float* zp = Z + (size_t)(rowbase + lane) * 32 + g * 8;
    *(float4*)(zp + 0) = make_float4(o[0], o[1], o[2], o[3]);
    *(float4*)(zp + 4) = make_float4(o[4], o[5], o[6], o[7]);
}

__device__ __forceinline__ float sigmoid_f(float v) {
    return 1.0f / (1.0f + __expf(-v));
}
__device__ __forceinline__ float tanh_fast(float v) {
    // 1 - 2/(e^{2v}+1); saturates correctly for |v| large.
    return 1.0f - 2.0f / (__expf(2.0f * v) + 1.0f);
}

// ---------------------------------------------------------------------------
// Kernel 2: gates = sigmoid(z @ W2 blocks + b2); LSTM elementwise.
//   Block: 256 threads, 64 rows. Thread owns hh = tid and tid+256; its W2
//   slice (4 gates x 8 q x 2 hh = 64 floats) lives in VGPRs for all 64 rows.
//   z row (32 floats) is uniform per row -> scalar loads -> v_fma(s,v,v).
// ---------------------------------------------------------------------------
__global__ __launch_bounds__(256, 4)
void k2_gates(const float* __restrict__ Z, const float* __restrict__ c,
              const float* __restrict__ W2, const float* __restrict__ b2,
              float* __restrict__ out) {
    const int tid     = threadIdx.x;
    const int rowbase = blockIdx.x * 64;

    // Preload W2/b2 slices for the two owned columns.
    float w2r[2][4][8];
    float b2r[2][4];
#pragma unroll
    for (int hi = 0; hi < 2; ++hi) {
        int hh = tid + 256 * hi;
#pragma unroll
        for (int g = 0; g < 4; ++g) {
            const float* wp = W2 + (size_t)(g * HID_DIM + hh) * NQ;
            float4 a = *(const float4*)(wp + 0);
            float4 b = *(const float4*)(wp + 4);
            w2r[hi][g][0] = a.x; w2r[hi][g][1] = a.y;
            w2r[hi][g][2] = a.z; w2r[hi][g][3] = a.w;
            w2r[hi][g][4] = b.x; w2r[hi][g][5] = b.y;
            w2r[hi][g][6] = b.z; w2r[hi][g][7] = b.w;
            b2r[hi][g] = b2[g * HID_DIM + hh];
        }
    }

    const size_t c_off = (size_t)B_TOTAL * HID_DIM;  // c_new offset in out

    for (int r = 0; r < 64; ++r) {
        const int row = rowbase + r;
        const float* zrow = Z + (size_t)row * 32;  // uniform -> s_load
        float zz[32];
#pragma unroll
        for (int t = 0; t < 8; ++t) {
            float4 zv = *(const float4*)(zrow + 4 * t);
            zz[4 * t + 0] = zv.x; zz[4 * t + 1] = zv.y;
            zz[4 * t + 2] = zv.z; zz[4 * t + 3] = zv.w;
        }
#pragma unroll
        for (int hi = 0; hi < 2; ++hi) {
            int hh = tid + 256 * hi;
            float cv = c[(size_t)row * HID_DIM + hh];
            float pre[4];
#pragma unroll
            for (int g = 0; g < 4; ++g) {
                float a = b2r[hi][g];
#pragma unroll
                for (int q = 0; q < 8; ++q)
                    a = fmaf(zz[g * 8 + q], w2r[hi][g][q], a);
                pre[g] = a;
            }
            float ig = sigmoid_f(pre[0]);
            float fg = sigmoid_f(pre[1]);
            float og = sigmoid_f(pre[2]);
            float gg = sigmoid_f(pre[3]);
            float cn = fg * cv + ig * gg;
            float hn = og * tanh_fast(cn);
            out[(size_t)row * HID_DIM + hh]         = hn;
            out[c_off + (size_t)row * HID_DIM + hh] = cn;
        }
    }
}

extern "C" void kernel_launch(void* const* d_in, const int* in_sizes, int n_in,
                              void* d_out, int out_size, void* d_ws, size_t ws_size,
                              hipStream_t stream) {
    const float* x  = (const float*)d_in[0];
    const float* h  = (const float*)d_in[1];
    const float* c  = (const float*)d_in[2];
    const float* W1 = (const float*)d_in[3];
    const float* b1 = (const float*)d_in[4];
    const float* W2 = (const float*)d_in[5];
    const float* b2 = (const float*)d_in[6];
    float* out = (float*)d_out;
    float* Z   = (float*)d_ws;  // 65536*32*4 = 8 MB scratch

    hipLaunchKernelGGL(k1_gemv, dim3(B_TOTAL / 64), dim3(256), 0, stream,
                       x, h, W1, b1, Z);
    hipLaunchKernelGGL(k2_gates, dim3(B_TOTAL / 64), dim3(256), 0, stream,
                       Z, c, W2, b2, out);
}